// Round 7
// baseline (145.181 us; speedup 1.0000x reference)
//
#include <hip/hip_runtime.h>

#define E_EDGES 8192
#define N_COMP  20000
#define N_IND   500
#define NKEYS   512

typedef short bf16x8 __attribute__((ext_vector_type(8)));
typedef float f32x4  __attribute__((ext_vector_type(4)));

static __device__ __forceinline__ unsigned short f2bf(float v) {
    unsigned u = __builtin_bit_cast(unsigned, v);
    u = (u + 0x7FFFu + ((u >> 16) & 1u)) >> 16;
    return (unsigned short)u;
}

static __device__ __forceinline__ void cvt8(const float* __restrict__ s,
                                            unsigned short* __restrict__ d) {
    float4 a = *(const float4*)s;
    float4 b = *(const float4*)(s + 4);
    bf16x8 o;
    o[0] = (short)f2bf(a.x); o[1] = (short)f2bf(a.y);
    o[2] = (short)f2bf(a.z); o[3] = (short)f2bf(a.w);
    o[4] = (short)f2bf(b.x); o[5] = (short)f2bf(b.y);
    o[6] = (short)f2bf(b.z); o[7] = (short)f2bf(b.w);
    *(bf16x8*)d = o;
}

// fp32x8 -> bf16x8 in registers
static __device__ __forceinline__ bf16x8 cvt8r(const float* __restrict__ s) {
    float4 a = *(const float4*)s;
    float4 b = *(const float4*)(s + 4);
    bf16x8 v;
    v[0] = (short)f2bf(a.x); v[1] = (short)f2bf(a.y);
    v[2] = (short)f2bf(a.z); v[3] = (short)f2bf(a.w);
    v[4] = (short)f2bf(b.x); v[5] = (short)f2bf(b.y);
    v[6] = (short)f2bf(b.z); v[7] = (short)f2bf(b.w);
    return v;
}

#define SWZ(r)   (((r) & 7) << 4)          // 128B-row tiles: 8 x 16B slots
#define SWZ4(r)  ((((r) >> 1) & 3) << 4)   // 64B-row tiles: 4 x 16B slots

// ---------------------------------------------------------------------------
// prep: block-range-dispatched preprocessing.
//  [0,32)    edge counting (csrc, ctgt)
//  [32,64)   Wc  -> bf16 (natural)
//  [64,96)   w_out -> bf16
//  [96,128)  Wc^T -> bf16
//  [128,144) Wi -> bf16 (natural)
//  [144,208) w_kv (= w_in rows 256:768) -> bf16
//  [208,220) composed biases beff[e] = w_in[e]·(e<256?bc:bi) + b_in[e]
// ---------------------------------------------------------------------------
__global__ __launch_bounds__(256) void prep(
    const int* __restrict__ src, const int* __restrict__ tgt,
    const float* __restrict__ Wc, const float* __restrict__ Wi,
    const float* __restrict__ w_out, const float* __restrict__ w_in,
    const float* __restrict__ bc, const float* __restrict__ bi,
    const float* __restrict__ b_in,
    float* __restrict__ csrc, float* __restrict__ ctgt,
    unsigned short* __restrict__ Wc_bf, unsigned short* __restrict__ wout_bf,
    unsigned short* __restrict__ WcT_bf, unsigned short* __restrict__ Wi_bf,
    unsigned short* __restrict__ wkv_bf, float* __restrict__ beff)
{
    const int bid = blockIdx.x, tid = threadIdx.x;
    if (bid < 32) {
        int e = bid * 256 + tid;
        atomicAdd(&csrc[src[e]], 1.0f);
        atomicAdd(&ctgt[tgt[e]], 1.0f);
    } else if (bid < 64) {
        long i = ((long)(bid - 32) * 256 + tid) * 8;
        cvt8(Wc + i, Wc_bf + i);
    } else if (bid < 96) {
        long i = ((long)(bid - 64) * 256 + tid) * 8;
        cvt8(w_out + i, wout_bf + i);
    } else if (bid < 128) {
        long o = ((long)(bid - 96) * 256 + tid) * 8;
        int c = (int)(o >> 8), d0 = (int)(o & 255);
        bf16x8 v;
#pragma unroll
        for (int j = 0; j < 8; j++) v[j] = (short)f2bf(Wc[(long)(d0 + j) * 256 + c]);
        *(bf16x8*)(WcT_bf + o) = v;
    } else if (bid < 144) {
        long i = ((long)(bid - 128) * 256 + tid) * 8;
        cvt8(Wi + i, Wi_bf + i);
    } else if (bid < 208) {
        long i = ((long)(bid - 144) * 256 + tid) * 8;
        cvt8(w_in + 65536 + i, wkv_bf + i);
    } else {
        int gi = (bid - 208) * 256 + tid;      // [0, 3072)
        int e = gi >> 2, q = gi & 3;
        const float* base = (e < 256) ? bc : bi;
        const float* wr = w_in + (long)e * 256 + q * 64;
        const float* br = base + q * 64;
        float s = 0.f;
#pragma unroll
        for (int j = 0; j < 64; j += 4) {
            float4 w4 = *(const float4*)(wr + j);
            float4 b4 = *(const float4*)(br + j);
            s += w4.x * b4.x + w4.y * b4.y + w4.z * b4.z + w4.w * b4.w;
        }
        s += __shfl_xor(s, 1);
        s += __shfl_xor(s, 2);
        if (q == 0) beff[e] = s + b_in[e];
    }
}

// ---------------------------------------------------------------------------
// fusedW: block-range dispatch. B-fragments from global (L2-hot) -> only one
// barrier total (after ih LDS write).
//  [0,4)   Wcq = w_in[0:256] @ WcT^T  -> bf16 [256][256]
//  [4,20)  per (rg, colh): ih = bf16(industry_x@Wi^T) in LDS;
//          colh=0: K rows  = ih @ wk^T + bk  -> Kbuf[512][256]
//          colh=1: VT cols = wv @ ih^T + bv  -> VTg[256][512] (swapped MFMA)
//  [20,99) finalize: lnm from ctgt; compact distinct-src list
// ---------------------------------------------------------------------------
__global__ __launch_bounds__(256) void fusedW(
    const float* __restrict__ w_in, const unsigned short* __restrict__ WcT_bf,
    const float* __restrict__ industry_x, const unsigned short* __restrict__ Wi_bf,
    const unsigned short* __restrict__ wkv_bf, const float* __restrict__ beff,
    const float* __restrict__ ctgt, const float* __restrict__ csrc,
    unsigned short* __restrict__ Wcq_bf, unsigned short* __restrict__ Kbuf,
    unsigned short* __restrict__ VTg,
    float* __restrict__ lnm, int* __restrict__ list, int* __restrict__ nlist)
{
    const int bid = blockIdx.x;
    if (bid >= 20) {
        int i = (bid - 20) * 256 + threadIdx.x;
        if (i < NKEYS) {
            float c = ctgt[i];
            lnm[i] = (c > 0.f) ? logf(c) : -1e30f;
        }
        if (i < N_COMP && csrc[i] > 0.f) {
            int k = atomicAdd(nlist, 1);
            list[k] = i;
        }
        return;
    }

    __shared__ char ihb[32768];   // ih [64][256] bf16, rows 512B, SWZ
    const int t = threadIdx.x, wv = t >> 6, lane = t & 63;
    const int g = lane >> 4, ln = lane & 15;

    if (bid < 4) {
        // ---- Wcq = w_in[0:256] @ WcT^T (no LDS, no barriers) ----
        const int bm = bid * 64;
        f32x4 acc[16];
#pragma unroll
        for (int i = 0; i < 16; i++) acc[i] = (f32x4){0.f, 0.f, 0.f, 0.f};
        for (int kc = 0; kc < 256; kc += 32) {
            bf16x8 af = cvt8r(w_in + (long)(bm + wv * 16 + ln) * 256 + kc + g * 8);
#pragma unroll
            for (int nj = 0; nj < 16; nj++) {
                bf16x8 bf = *(const bf16x8*)(WcT_bf + (long)(nj * 16 + ln) * 256 + kc + g * 8);
                acc[nj] = __builtin_amdgcn_mfma_f32_16x16x32_bf16(af, bf, acc[nj], 0, 0, 0);
            }
        }
#pragma unroll
        for (int nj = 0; nj < 16; nj++)
#pragma unroll
            for (int r = 0; r < 4; r++)
                Wcq_bf[(long)(bm + wv * 16 + g * 4 + r) * 256 + nj * 16 + ln] =
                    f2bf(acc[nj][r]);
        return;
    }

    // ---- KV blocks ----
    const int rg = (bid - 4) >> 1, colh = (bid - 4) & 1;

    // phase 1: ih = industry_x @ Wi^T  (64 rows x 256, K=128)
    {
        f32x4 a1[16];
#pragma unroll
        for (int i = 0; i < 16; i++) a1[i] = (f32x4){0.f, 0.f, 0.f, 0.f};
        int arow = rg * 64 + wv * 16 + ln; if (arow > N_IND - 1) arow = N_IND - 1;
        for (int kc = 0; kc < 128; kc += 32) {
            bf16x8 af = cvt8r(industry_x + (long)arow * 128 + kc + g * 8);
#pragma unroll
            for (int nj = 0; nj < 16; nj++) {
                bf16x8 bf = *(const bf16x8*)(Wi_bf + (long)(nj * 16 + ln) * 128 + kc + g * 8);
                a1[nj] = __builtin_amdgcn_mfma_f32_16x16x32_bf16(af, bf, a1[nj], 0, 0, 0);
            }
        }
#pragma unroll
        for (int nj = 0; nj < 16; nj++)
#pragma unroll
            for (int r = 0; r < 4; r++) {
                int row = wv * 16 + g * 4 + r, col = nj * 16 + ln;
                *(unsigned short*)(ihb + ((row * 512 + col * 2) ^ SWZ(row))) =
                    f2bf(a1[nj][r]);
            }
    }
    __syncthreads();

    if (colh == 0) {
        // K = ih @ wk^T + bk
        f32x4 a2[16];
#pragma unroll
        for (int i = 0; i < 16; i++) a2[i] = (f32x4){0.f, 0.f, 0.f, 0.f};
        for (int kc = 0; kc < 256; kc += 32) {
            int row = wv * 16 + ln;
            bf16x8 af = *(bf16x8*)(ihb + ((row * 512 + (kc + g * 8) * 2) ^ SWZ(row)));
#pragma unroll
            for (int nj = 0; nj < 16; nj++) {
                bf16x8 bf = *(const bf16x8*)(wkv_bf + (long)(nj * 16 + ln) * 256 + kc + g * 8);
                a2[nj] = __builtin_amdgcn_mfma_f32_16x16x32_bf16(af, bf, a2[nj], 0, 0, 0);
            }
        }
#pragma unroll
        for (int nj = 0; nj < 16; nj++)
#pragma unroll
            for (int r = 0; r < 4; r++) {
                int R = rg * 64 + wv * 16 + g * 4 + r, n = nj * 16 + ln;
                Kbuf[(long)R * 256 + n] = f2bf(a2[nj][r] + beff[256 + n]);
            }
    } else {
        // VT = (ih @ wv^T)^T computed directly: C[n][R] = mfma(A=wv, B=ih)
        const unsigned short* wp = wkv_bf + 65536;   // wv rows [256][256]
        f32x4 a2[16];
#pragma unroll
        for (int i = 0; i < 16; i++) a2[i] = (f32x4){0.f, 0.f, 0.f, 0.f};
        for (int kc = 0; kc < 256; kc += 32) {
#pragma unroll
            for (int mi = 0; mi < 4; mi++) {
                bf16x8 af = *(const bf16x8*)(wp + (long)(wv * 64 + mi * 16 + ln) * 256 + kc + g * 8);
#pragma unroll
                for (int t4 = 0; t4 < 4; t4++) {
                    int row = t4 * 16 + ln;
                    bf16x8 bf = *(bf16x8*)(ihb + ((row * 512 + (kc + g * 8) * 2) ^ SWZ(row)));
                    a2[mi * 4 + t4] = __builtin_amdgcn_mfma_f32_16x16x32_bf16(af, bf, a2[mi * 4 + t4], 0, 0, 0);
                }
            }
        }
#pragma unroll
        for (int mi = 0; mi < 4; mi++)
#pragma unroll
            for (int t4 = 0; t4 < 4; t4++)
#pragma unroll
                for (int r = 0; r < 4; r++) {
                    int nrow = wv * 64 + mi * 16 + g * 4 + r;
                    VTg[(long)nrow * 512 + rg * 64 + t4 * 16 + ln] =
                        f2bf(a2[mi * 4 + t4][r] + beff[512 + nrow]);
                }
    }
}

// ---------------------------------------------------------------------------
// megattn v2: 16 listed companies per block; wave h = head h.
//  1. coop-stage x[16][256] -> LDS; barrier
//  2. per-wave Q = x @ Wcq_h^T (B-frags global), q->LDS->qf regs; barrier
//  3. per-wave flash attn, 16 tiles x 32 keys, K/VT frags DIRECT FROM GLOBAL
//     (L2-resident), P via 1KB wave-private LDS; NO barriers in loop
//  4. ctx_h overwrites own q slot; barrier
//  5. out-proj cols [64h,64h+64) (B-frags global) -> pooled rows (no atomics)
// ---------------------------------------------------------------------------
__global__ __launch_bounds__(256) void megattn(
    const float* __restrict__ company_x,
    const unsigned short* __restrict__ Wcq,
    const float* __restrict__ beff,
    const unsigned short* __restrict__ Kbuf,
    const unsigned short* __restrict__ VTg,
    const float* __restrict__ lnm,
    const unsigned short* __restrict__ wout,
    const float* __restrict__ b_out,
    const int* __restrict__ list, const int* __restrict__ nlist,
    float* __restrict__ pooled)
{
    const int M = *nlist;
    const int bm = blockIdx.x * 16;
    if (bm >= M) return;

    __shared__ char lds[16384];
    const int t = threadIdx.x, h = t >> 6, lane = t & 63;
    const int g = lane >> 4, ln = lane & 15;
    char* qbase = lds + h * 2048;           // per-wave [16][64] bf16, rows 128B
    char* xbase = lds + 8192;               // [16][256] bf16, rows 512B (Q phase)
    char* pbase = lds + 8192 + h * 1024;    // per-wave P [16][32] bf16, rows 64B

    // ---- 1. stage x ----
    {
        int row = t >> 4, c0 = (t & 15) * 16;
        int mr = bm + row; if (mr > M - 1) mr = M - 1;
        const float* src = company_x + (long)list[mr] * 256 + c0;
        bf16x8 v0 = cvt8r(src);
        bf16x8 v1 = cvt8r(src + 8);
        *(bf16x8*)(xbase + ((row * 512 + c0 * 2) ^ SWZ(row))) = v0;
        *(bf16x8*)(xbase + ((row * 512 + c0 * 2 + 16) ^ SWZ(row))) = v1;
    }
    __syncthreads();

    // ---- 2. Q (per wave) ----
    bf16x8 qf0, qf1;
    {
        f32x4 qa[4];
#pragma unroll
        for (int i = 0; i < 4; i++) qa[i] = (f32x4){0.f, 0.f, 0.f, 0.f};
        for (int kc = 0; kc < 256; kc += 32) {
            bf16x8 af = *(bf16x8*)(xbase + ((ln * 512 + (kc + g * 8) * 2) ^ SWZ(ln)));
#pragma unroll
            for (int nj = 0; nj < 4; nj++) {
                bf16x8 bf = *(const bf16x8*)(Wcq + (long)(h * 64 + nj * 16 + ln) * 256 + kc + g * 8);
                qa[nj] = __builtin_amdgcn_mfma_f32_16x16x32_bf16(af, bf, qa[nj], 0, 0, 0);
            }
        }
#pragma unroll
        for (int nj = 0; nj < 4; nj++)
#pragma unroll
            for (int r = 0; r < 4; r++) {
                int row = g * 4 + r, col = nj * 16 + ln;
                *(unsigned short*)(qbase + ((row * 128 + col * 2) ^ SWZ(row))) =
                    f2bf((qa[nj][r] + beff[h * 64 + col]) * 0.125f);
            }
        qf0 = *(bf16x8*)(qbase + ((ln * 128 + g * 16) ^ SWZ(ln)));
        qf1 = *(bf16x8*)(qbase + ((ln * 128 + 64 + g * 16) ^ SWZ(ln)));
    }
    __syncthreads();   // x area dead; P (aliased) becomes live

    // ---- 3. flash attention, 32 keys per tile ----
    f32x4 acc[4];
#pragma unroll
    for (int i = 0; i < 4; i++) acc[i] = (f32x4){0.f, 0.f, 0.f, 0.f};
    float mreg[4] = {-1e30f, -1e30f, -1e30f, -1e30f};
    float lreg[4] = {0.f, 0.f, 0.f, 0.f};

    for (int kt = 0; kt < 16; kt++) {
        // S = Q K^T + ln(mult)  (K frags direct from global, L2-hot)
        f32x4 S[2];
#pragma unroll
        for (int sub = 0; sub < 2; sub++) {
            const unsigned short* kr =
                Kbuf + (long)(kt * 32 + sub * 16 + ln) * 256 + h * 64 + g * 8;
            bf16x8 k0 = *(const bf16x8*)(kr);
            bf16x8 k1 = *(const bf16x8*)(kr + 32);
            f32x4 s = (f32x4){0.f, 0.f, 0.f, 0.f};
            s = __builtin_amdgcn_mfma_f32_16x16x32_bf16(qf0, k0, s, 0, 0, 0);
            s = __builtin_amdgcn_mfma_f32_16x16x32_bf16(qf1, k1, s, 0, 0, 0);
            float lmv = lnm[kt * 32 + sub * 16 + ln];
#pragma unroll
            for (int r = 0; r < 4; r++) s[r] += lmv;
            S[sub] = s;
        }

        // online softmax (rows live in 16-lane groups)
        float tm[4];
#pragma unroll
        for (int r = 0; r < 4; r++) tm[r] = fmaxf(S[0][r], S[1][r]);
#pragma unroll
        for (int st = 1; st < 16; st <<= 1)
#pragma unroll
            for (int r = 0; r < 4; r++) tm[r] = fmaxf(tm[r], __shfl_xor(tm[r], st));

        float corr[4];
#pragma unroll
        for (int r = 0; r < 4; r++) {
            float mn = fmaxf(mreg[r], tm[r]);
            corr[r] = __expf(mreg[r] - mn);
            mreg[r] = mn;
        }
        float ps[4] = {0.f, 0.f, 0.f, 0.f};
#pragma unroll
        for (int sub = 0; sub < 2; sub++)
#pragma unroll
            for (int r = 0; r < 4; r++) {
                float p = __expf(S[sub][r] - mreg[r]);
                S[sub][r] = p;
                ps[r] += p;
            }
#pragma unroll
        for (int st = 1; st < 16; st <<= 1)
#pragma unroll
            for (int r = 0; r < 4; r++) ps[r] += __shfl_xor(ps[r], st);
#pragma unroll
        for (int r = 0; r < 4; r++) lreg[r] = lreg[r] * corr[r] + ps[r];
#pragma unroll
        for (int i = 0; i < 4; i++)
#pragma unroll
            for (int r = 0; r < 4; r++) acc[i][r] *= corr[r];

        // P -> wave-private LDS (A-operand relayout)
#pragma unroll
        for (int sub = 0; sub < 2; sub++)
#pragma unroll
            for (int r = 0; r < 4; r++) {
                int row = g * 4 + r;
                *(unsigned short*)(pbase + ((row * 64 + (sub * 16 + ln) * 2) ^ SWZ4(row))) =
                    f2bf(S[sub][r]);
            }
        bf16x8 pa = *(bf16x8*)(pbase + ((ln * 64 + g * 16) ^ SWZ4(ln)));

        // PV (VT frags direct from global, L2-hot)
#pragma unroll
        for (int t4 = 0; t4 < 4; t4++) {
            bf16x8 vf = *(const bf16x8*)(
                VTg + (long)(h * 64 + t4 * 16 + ln) * 512 + kt * 32 + g * 8);
            acc[t4] = __builtin_amdgcn_mfma_f32_16x16x32_bf16(pa, vf, acc[t4], 0, 0, 0);
        }
    }

    // ---- 4. ctx_h overwrites own q slot ----
#pragma unroll
    for (int t4 = 0; t4 < 4; t4++)
#pragma unroll
        for (int r = 0; r < 4; r++) {
            int row = g * 4 + r, col = t4 * 16 + ln;
            *(unsigned short*)(qbase + ((row * 128 + col * 2) ^ SWZ(row))) =
                f2bf(acc[t4][r] / lreg[r]);
        }
    __syncthreads();

    // ---- 5. out-proj cols [64h, 64h+64) -> pooled ----
    {
        f32x4 oa[4];
#pragma unroll
        for (int i = 0; i < 4; i++) oa[i] = (f32x4){0.f, 0.f, 0.f, 0.f};
        for (int kc = 0; kc < 256; kc += 32) {
            int hs = kc >> 6;
            int off = (kc & 63) + g * 8;
            bf16x8 af = *(bf16x8*)(lds + hs * 2048 + ((ln * 128 + off * 2) ^ SWZ(ln)));
#pragma unroll
            for (int nj = 0; nj < 4; nj++) {
                bf16x8 bf = *(const bf16x8*)(wout + (long)(h * 64 + nj * 16 + ln) * 256 + kc + g * 8);
                oa[nj] = __builtin_amdgcn_mfma_f32_16x16x32_bf16(af, bf, oa[nj], 0, 0, 0);
            }
        }
#pragma unroll
        for (int nj = 0; nj < 4; nj++) {
            int n = h * 64 + nj * 16 + ln;
            float bv = b_out[n];
#pragma unroll
            for (int r = 0; r < 4; r++) {
                int R = bm + g * 4 + r;
                if (R < M)
                    pooled[(long)list[R] * 256 + n] = oa[nj][r] + bv;
            }
        }
    }
}

// ---------------------------------------------------------------------------
// gemm_ln: company GEMM (company_x @ Wc^T + bc) fused residual+pooled+LN.
// ---------------------------------------------------------------------------
__global__ __launch_bounds__(256) void gemm_ln(
    const float* __restrict__ A, const unsigned short* __restrict__ W,
    const float* __restrict__ bias,
    const float* __restrict__ pooled, const float* __restrict__ csrc,
    const float* __restrict__ gamma, const float* __restrict__ beta,
    float* __restrict__ out, int M, int K)
{
    __shared__ unsigned short As[64 * 32];
    __shared__ unsigned short Ws[256 * 32];
    char* abase = (char*)As;
    char* wbase = (char*)Ws;

    const int bm = blockIdx.x * 64;
    const int t = threadIdx.x;
    const int wv = t >> 6, lane = t & 63, g = lane >> 4, ln = lane & 15;

    f32x4 acc[16];
#pragma unroll
    for (int i = 0; i < 16; i++) acc[i] = (f32x4){0.f, 0.f, 0.f, 0.f};

    const int sr = t >> 2;
    const int sc = (t & 3) * 8;
    int arow = bm + sr; if (arow > M - 1) arow = M - 1;
    const float* aptr = A + (long)arow * K + sc;

    for (int kc = 0; kc < K; kc += 32) {
        __syncthreads();
        *(bf16x8*)(abase + ((sr * 64 + sc * 2) ^ SWZ(sr))) = cvt8r(aptr + kc);
#pragma unroll
        for (int p = 0; p < 4; p++) {
            int r = p * 64 + sr;
            *(bf16x8*)(wbase + ((r * 64 + sc * 2) ^ SWZ(r))) =
                *(const bf16x8*)(W + (long)r * K + kc + sc);
        }
        __syncthreads();

        const int ar = wv * 16 + ln;
        bf16x8 af = *(bf16x8*)(abase + ((ar * 64 + g * 16) ^ SWZ(ar)));
#pragma unroll
        for (int nj = 0; nj < 16; nj++) {
            int wr = nj * 16 + ln;
            bf16x8 bf = *(bf16x8*)(wbase + ((wr * 64 + g * 16) ^ SWZ(wr)));
            acc[nj] = __builtin_amdgcn_mfma_f32_16x16x32_bf16(af, bf, acc[nj], 0, 0, 0);
        }
    }

#pragma unroll
    for (int r = 0; r < 4; r++) {
        int R = bm + wv * 16 + g * 4 + r;
        bool valid = R < M;
        int Rc = valid ? R : 0;
        float cnt = csrc[Rc];
        float factor = (valid && cnt > 0.f) ? cnt / (cnt + 1e-6f) : 0.f;

        float v[16];
        float sum = 0.f, sq = 0.f;
#pragma unroll
        for (int nj = 0; nj < 16; nj++) {
            int n = nj * 16 + ln;
            float x = acc[nj][r] + bias[n] + factor * pooled[(long)Rc * 256 + n];
            v[nj] = x;
            sum += x;
            sq  += x * x;
        }
#pragma unroll
        for (int st = 1; st < 16; st <<= 1) {
            sum += __shfl_xor(sum, st);
            sq  += __shfl_xor(sq,  st);
        }
        float mean = sum * (1.0f / 256.0f);
        float var  = sq * (1.0f / 256.0f) - mean * mean;
        float rstd = rsqrtf(var + 1e-5f);
        if (valid) {
#pragma unroll
            for (int nj = 0; nj < 16; nj++) {
                int n = nj * 16 + ln;
                out[(long)R * 256 + n] = (v[nj] - mean) * rstd * gamma[n] + beta[n];
            }
        }
    }
}

// ---------------------------------------------------------------------------
extern "C" void kernel_launch(void* const* d_in, const int* in_sizes, int n_in,
                              void* d_out, int out_size, void* d_ws, size_t ws_size,
                              hipStream_t stream)
{
    const float* company_x  = (const float*)d_in[0];
    const float* industry_x = (const float*)d_in[1];
    const int*   edge       = (const int*)d_in[2];
    const float* Wc         = (const float*)d_in[3];
    const float* bc         = (const float*)d_in[4];
    const float* Wi         = (const float*)d_in[5];
    const float* bi         = (const float*)d_in[6];
    const float* w_in       = (const float*)d_in[7];
    const float* b_in       = (const float*)d_in[8];
    const float* w_out      = (const float*)d_in[9];
    const float* b_out      = (const float*)d_in[10];
    const float* gamma      = (const float*)d_in[11];
    const float* beta       = (const float*)d_in[12];
    float* out = (float*)d_out;

    const int* src = edge;
    const int* tgt = edge + E_EDGES;

    // workspace carve (float units)
    float* wf = (float*)d_ws;
    size_t o = 0;
    unsigned short* Wc_bf   = (unsigned short*)(wf + o); o += 32768;  // 256x256
    unsigned short* wout_bf = (unsigned short*)(wf + o); o += 32768;
    unsigned short* WcT_bf  = (unsigned short*)(wf + o); o += 32768;
    unsigned short* Wi_bf   = (unsigned short*)(wf + o); o += 16384;  // 256x128
    unsigned short* wkv_bf  = (unsigned short*)(wf + o); o += 65536;  // 512x256
    unsigned short* Wcq_bf  = (unsigned short*)(wf + o); o += 32768;
    unsigned short* Kbuf    = (unsigned short*)(wf + o); o += 65536;  // 512x256
    unsigned short* VTg     = (unsigned short*)(wf + o); o += 65536;  // 256x512
    float* pooled           = wf + o; o += (size_t)N_COMP * 256;
    float* beff             = wf + o; o += 768;
    float* lnm              = wf + o; o += NKEYS;
    int*   list             = (int*)(wf + o); o += E_EDGES;
    // contiguous zeroed region: csrc | ctgt | nlist
    float* csrc             = wf + o; o += N_COMP;
    float* ctgt             = wf + o; o += NKEYS;
    int*   nlist            = (int*)(wf + o); o += 4;

    dim3 blk(256);

    hipMemsetAsync(csrc, 0, (N_COMP + NKEYS + 4) * sizeof(float), stream);

    prep<<<dim3(220), blk, 0, stream>>>(
        src, tgt, Wc, Wi, w_out, w_in, bc, bi, b_in,
        csrc, ctgt, Wc_bf, wout_bf, WcT_bf, Wi_bf, wkv_bf, beff);

    fusedW<<<dim3(99), blk, 0, stream>>>(
        w_in, WcT_bf, industry_x, Wi_bf, wkv_bf, beff, ctgt, csrc,
        Wcq_bf, Kbuf, VTg, lnm, list, nlist);

    megattn<<<dim3(512), blk, 0, stream>>>(
        company_x, Wcq_bf, beff, Kbuf, VTg, lnm, wout_bf, b_out,
        list, nlist, pooled);

    gemm_ln<<<dim3((N_COMP + 63) / 64), blk, 0, stream>>>(
        company_x, Wc_bf, bc, pooled, csrc, gamma, beta, out, N_COMP, 256);
}